// Round 4
// baseline (142.435 us; speedup 1.0000x reference)
//
#include <hip/hip_runtime.h>
#include <math.h>

// FM layer, flat decomposition:
//  zero_ws    : zero the [batch][18] accumulator table (ws is re-poisoned 0xAA).
//  fm_gather  : one LANE per nnz element (coalesced ids/segs, 2-deep load chain,
//               100% lane util). Per-wave segmented inclusive scan (segs sorted ->
//               same-segment runs are lane-contiguous), run-tail lanes atomicAdd
//               their 18 partials (sum[16], sum(x^2), sum(lw)) into ws. ~2.3
//               runs/wave -> ~525K atomics total, L2-resident.
//  fm_epilogue: per segment: logit = bias + slin + 0.5*(|sum|^2 - ssq); sigmoid.

#define WS_STRIDE 18

__global__ __launch_bounds__(256) void zero_ws_kernel(float* __restrict__ ws, int n)
{
    const int i = blockIdx.x * 256 + threadIdx.x;
    if (i < n) ws[i] = 0.f;
}

__global__ __launch_bounds__(256) void fm_gather_kernel(
    const int* __restrict__ ids,
    const int* __restrict__ segs,
    const float* __restrict__ lw,
    const float* __restrict__ cw,
    float* __restrict__ ws,
    int nnz)
{
    const int i    = blockIdx.x * 256 + threadIdx.x;
    const int lane = threadIdx.x & 63;

    int seg = -1;
    float v[18];
    #pragma unroll
    for (int d = 0; d < 18; ++d) v[d] = 0.f;

    if (i < nnz) {
        seg = segs[i];
        const int id = ids[i];
        const float* row = cw + ((size_t)id << 4);
        const float4 x0 = *reinterpret_cast<const float4*>(row);
        const float4 x1 = *reinterpret_cast<const float4*>(row + 4);
        const float4 x2 = *reinterpret_cast<const float4*>(row + 8);
        const float4 x3 = *reinterpret_cast<const float4*>(row + 12);
        const float l  = lw[id];
        v[ 0] = x0.x; v[ 1] = x0.y; v[ 2] = x0.z; v[ 3] = x0.w;
        v[ 4] = x1.x; v[ 5] = x1.y; v[ 6] = x1.z; v[ 7] = x1.w;
        v[ 8] = x2.x; v[ 9] = x2.y; v[10] = x2.z; v[11] = x2.w;
        v[12] = x3.x; v[13] = x3.y; v[14] = x3.z; v[15] = x3.w;
        float ssq = 0.f;
        #pragma unroll
        for (int d = 0; d < 16; ++d) ssq = fmaf(v[d], v[d], ssq);
        v[16] = ssq;
        v[17] = l;
    }

    // Segmented inclusive scan over the wave (Hillis-Steele).
    // segs sorted => equal-segment lanes are contiguous, so the guard
    // (lane-k has same seg) implies all lanes in between do too.
    #pragma unroll
    for (int k = 1; k < 64; k <<= 1) {
        const int oseg = __shfl_up(seg, k, 64);
        const bool take = (lane >= k) && (oseg == seg);
        #pragma unroll
        for (int d = 0; d < 18; ++d) {
            const float ov = __shfl_up(v[d], k, 64);
            if (take) v[d] += ov;
        }
    }

    // Run tails hold the complete run sum; merge into ws with atomics.
    const int nseg = __shfl_down(seg, 1, 64);
    const bool tail = (lane == 63) || (nseg != seg);
    if (tail && seg >= 0) {
        float* dst = ws + (size_t)seg * WS_STRIDE;
        #pragma unroll
        for (int d = 0; d < 18; ++d) atomicAdd(dst + d, v[d]);
    }
}

__global__ __launch_bounds__(256) void fm_epilogue_kernel(
    const float* __restrict__ ws,
    const float* __restrict__ bias,
    float* __restrict__ out,
    int batch)
{
    const int b = blockIdx.x * 256 + threadIdx.x;
    if (b >= batch) return;
    const float* a = ws + (size_t)b * WS_STRIDE;
    float q = 0.f;
    #pragma unroll
    for (int d = 0; d < 16; ++d) q = fmaf(a[d], a[d], q);
    const float logit = bias[0] + a[17] + 0.5f * (q - a[16]);
    out[b]             = logit;   // logits
    out[batch + b]     = logit;   // + log(NEG_SAMPLING_RATE=1) == 0
    out[2 * batch + b] = 1.0f / (1.0f + expf(-logit));
}

extern "C" void kernel_launch(void* const* d_in, const int* in_sizes, int n_in,
                              void* d_out, int out_size, void* d_ws, size_t ws_size,
                              hipStream_t stream) {
    const int*   ids  = (const int*)d_in[0];
    const int*   segs = (const int*)d_in[1];
    const float* bias = (const float*)d_in[3];
    const float* lw   = (const float*)d_in[4];
    const float* cw   = (const float*)d_in[5];
    float*       out  = (float*)d_out;

    const int nnz   = in_sizes[0];
    const int batch = out_size / 3;

    float* ws = (float*)d_ws;  // [batch][18] accumulators
    const int ws_n = batch * WS_STRIDE;

    zero_ws_kernel<<<(ws_n + 255) / 256, 256, 0, stream>>>(ws, ws_n);
    fm_gather_kernel<<<(nnz + 255) / 256, 256, 0, stream>>>(ids, segs, lw, cw, ws, nnz);
    fm_epilogue_kernel<<<(batch + 255) / 256, 256, 0, stream>>>(ws, bias, out, batch);
}

// Round 5
// 123.393 us; speedup vs baseline: 1.1543x; 1.1543x over previous
//
#include <hip/hip_runtime.h>
#include <math.h>

// FM layer: logits = bias + segsum(lw[ids]) + 0.5*sum_d((segsum x_d)^2 - segsum(x_d^2))
// outputs: [logits, logits_adjusted, probabilities], each [B], B = out_size/3.
//
// R4 = R1 structure (starts table, wave-per-segment, register accumulation)
//    + QUAD gather layout: 4 lanes per element, each lane loads 16B of the 64B
//      row -> the 4 lanes of a quad hit the SAME 128B line and coalesce to one
//      memory request per element (vs 4 in row-per-lane layout). 2x unrolled.

__global__ __launch_bounds__(256) void seg_starts_kernel(
    const int* __restrict__ segs, int* __restrict__ starts, int nnz, int batch)
{
    const int i = blockIdx.x * blockDim.x + threadIdx.x;
    if (i >= nnz) return;
    const int cur = segs[i];
    if (i == 0) {
        for (int b = 0; b <= cur; ++b) starts[b] = 0;
    } else {
        const int prev = segs[i - 1];
        for (int b = prev + 1; b <= cur; ++b) starts[b] = i;
    }
    if (i == nnz - 1) {
        for (int b = cur + 1; b <= batch; ++b) starts[b] = nnz;
    }
}

__global__ __launch_bounds__(256) void fm_fused_kernel(
    const int* __restrict__ ids,
    const int* __restrict__ starts,
    const float* __restrict__ bias,
    const float* __restrict__ lw,
    const float* __restrict__ cw,
    float* __restrict__ out,
    int batch)
{
    const int wave = threadIdx.x >> 6;      // wave in block: 0..3
    const int wl   = threadIdx.x & 63;      // lane in wave
    const int b    = blockIdx.x * 4 + wave; // segment this wave owns
    if (b >= batch) return;

    const int start = starts[b];
    const int end   = starts[b + 1];

    // quad layout: element slot e = wl>>2 (16 per iter), component slot c = wl&3.
    const int e = wl >> 2;
    const int c = wl & 3;

    float4 sd = make_float4(0.f, 0.f, 0.f, 0.f);
    float ssq = 0.f, slin = 0.f;

    int i = start + e;
    // 2x unrolled: 32 elements in flight per iteration.
    for (; i + 16 < end; i += 32) {
        const int id0 = ids[i];
        const int id1 = ids[i + 16];
        const float4 x0 = *reinterpret_cast<const float4*>(cw + ((size_t)id0 << 4) + (c << 2));
        const float4 x1 = *reinterpret_cast<const float4*>(cw + ((size_t)id1 << 4) + (c << 2));
        if (c == 0) slin += lw[id0] + lw[id1];
        sd.x += x0.x; sd.y += x0.y; sd.z += x0.z; sd.w += x0.w;
        sd.x += x1.x; sd.y += x1.y; sd.z += x1.z; sd.w += x1.w;
        ssq = fmaf(x0.x, x0.x, ssq); ssq = fmaf(x0.y, x0.y, ssq);
        ssq = fmaf(x0.z, x0.z, ssq); ssq = fmaf(x0.w, x0.w, ssq);
        ssq = fmaf(x1.x, x1.x, ssq); ssq = fmaf(x1.y, x1.y, ssq);
        ssq = fmaf(x1.z, x1.z, ssq); ssq = fmaf(x1.w, x1.w, ssq);
    }
    if (i < end) {
        const int id0 = ids[i];
        const float4 x0 = *reinterpret_cast<const float4*>(cw + ((size_t)id0 << 4) + (c << 2));
        if (c == 0) slin += lw[id0];
        sd.x += x0.x; sd.y += x0.y; sd.z += x0.z; sd.w += x0.w;
        ssq = fmaf(x0.x, x0.x, ssq); ssq = fmaf(x0.y, x0.y, ssq);
        ssq = fmaf(x0.z, x0.z, ssq); ssq = fmaf(x0.w, x0.w, ssq);
    }

    // Reduce across the 16 element slots (lanes sharing the same c).
    #pragma unroll
    for (int m = 4; m <= 32; m <<= 1) {
        sd.x += __shfl_xor(sd.x, m);
        sd.y += __shfl_xor(sd.y, m);
        sd.z += __shfl_xor(sd.z, m);
        sd.w += __shfl_xor(sd.w, m);
        ssq  += __shfl_xor(ssq,  m);
        slin += __shfl_xor(slin, m);
    }
    // Each lane now holds complete summed[] for its 4 components.
    float q = sd.x*sd.x + sd.y*sd.y + sd.z*sd.z + sd.w*sd.w;
    #pragma unroll
    for (int m = 1; m <= 2; m <<= 1) {
        q    += __shfl_xor(q,    m);
        ssq  += __shfl_xor(ssq,  m);
        slin += __shfl_xor(slin, m);
    }

    if (wl == 0) {
        const float logit = bias[0] + slin + 0.5f * (q - ssq);
        out[b]             = logit;   // logits
        out[batch + b]     = logit;   // + log(NEG_SAMPLING_RATE=1) == 0
        out[2 * batch + b] = 1.0f / (1.0f + expf(-logit));
    }
}

extern "C" void kernel_launch(void* const* d_in, const int* in_sizes, int n_in,
                              void* d_out, int out_size, void* d_ws, size_t ws_size,
                              hipStream_t stream) {
    const int*   ids  = (const int*)d_in[0];
    const int*   segs = (const int*)d_in[1];
    const float* bias = (const float*)d_in[3];
    const float* lw   = (const float*)d_in[4];
    const float* cw   = (const float*)d_in[5];
    float*       out  = (float*)d_out;

    const int nnz   = in_sizes[0];
    const int batch = out_size / 3;

    int* starts = (int*)d_ws;  // batch+1 ints, fully rewritten every launch

    seg_starts_kernel<<<(nnz + 255) / 256, 256, 0, stream>>>(segs, starts, nnz, batch);

    const int waves_per_block = 4;
    const int grid = (batch + waves_per_block - 1) / waves_per_block;
    fm_fused_kernel<<<grid, 256, 0, stream>>>(ids, starts, bias, lw, cw, out, batch);
}